// Round 1
// baseline (471.445 us; speedup 1.0000x reference)
//
#include <hip/hip_runtime.h>
#include <hip/hip_bf16.h>
#include <math.h>

#define D 128

typedef __attribute__((ext_vector_type(8))) short bf16x8;
typedef __attribute__((ext_vector_type(4))) float f32x4;

__device__ __forceinline__ unsigned short f2bf(float f){
  unsigned u = __float_as_uint(f);
  u = (u + 0x7FFFu + ((u >> 16) & 1u)) >> 16;
  return (unsigned short)u;
}
__device__ __forceinline__ float bf2f(unsigned short h){
  return __uint_as_float(((unsigned)h) << 16);
}
__device__ __forceinline__ float gelu_exact(float v){
  return 0.5f * v * (1.0f + erff(v * 0.70710678118654752f));
}

// ---- weights fp32 -> bf16 (6 matrices of 128x128) ----
__global__ void k_wcvt(const float* s0, const float* s1, const float* s2,
                       const float* s3, const float* s4, const float* s5,
                       unsigned short* dst){
  const float* srcs[6] = {s0, s1, s2, s3, s4, s5};
  int m = blockIdx.y;
  int i = blockIdx.x * 256 + threadIdx.x;   // 0..16383
  dst[m * 16384 + i] = f2bf(srcs[m][i]);
}

// ---- CSR build ----
__global__ void k_hist(const int* __restrict__ dstn, int* __restrict__ deg, int E){
  int e = blockIdx.x * 256 + threadIdx.x;
  if (e < E) atomicAdd(&deg[dstn[e]], 1);
}

__global__ __launch_bounds__(256) void k_scan1(const int* __restrict__ deg,
                                               int* __restrict__ off,
                                               int* __restrict__ partials, int n){
  __shared__ int sm[256];
  int t = threadIdx.x;
  int base = blockIdx.x * 1024 + t * 4;
  int d[4];
  #pragma unroll
  for (int i = 0; i < 4; i++) d[i] = (base + i < n) ? deg[base + i] : 0;
  int s = d[0] + d[1] + d[2] + d[3];
  sm[t] = s; __syncthreads();
  for (int ofs = 1; ofs < 256; ofs <<= 1){
    int v = (t >= ofs) ? sm[t - ofs] : 0;
    __syncthreads();
    sm[t] += v;
    __syncthreads();
  }
  int run = sm[t] - s;
  #pragma unroll
  for (int i = 0; i < 4; i++){ if (base + i < n) off[base + i] = run; run += d[i]; }
  if (t == 255) partials[blockIdx.x] = sm[255];
}

__global__ void k_scan2(const int* __restrict__ partials, int* __restrict__ poff, int nb){
  __shared__ int sm[64];
  int t = threadIdx.x;
  int v = (t < nb) ? partials[t] : 0;
  sm[t] = v; __syncthreads();
  for (int ofs = 1; ofs < 64; ofs <<= 1){
    int u = (t >= ofs) ? sm[t - ofs] : 0;
    __syncthreads();
    sm[t] += u;
    __syncthreads();
  }
  if (t < nb) poff[t] = sm[t] - v;
}

__global__ void k_scan3(int* __restrict__ off, int* __restrict__ run,
                        const int* __restrict__ poff, int n, int E){
  int i = blockIdx.x * 256 + threadIdx.x;
  if (i < n){
    int v = off[i] + poff[i >> 10];
    off[i] = v; run[i] = v;
  }
  if (i == 0) off[n] = E;
}

__global__ void k_scatter(const int* __restrict__ srcn, const int* __restrict__ dstn,
                          int* __restrict__ run, int* __restrict__ csr, int E){
  int e = blockIdx.x * 256 + threadIdx.x;
  if (e < E){
    int pos = atomicAdd(&run[dstn[e]], 1);
    csr[pos] = srcn[e];
  }
}

// ---- mean aggregation: one wave per node ----
__global__ __launch_bounds__(256) void k_agg(const unsigned short* __restrict__ h,
                                             const int* __restrict__ off,
                                             const int* __restrict__ csr,
                                             unsigned short* __restrict__ out, int N){
  int gw = (blockIdx.x * 256 + threadIdx.x) >> 6;
  int lane = threadIdx.x & 63;
  if (gw >= N) return;
  int s0 = off[gw], s1 = off[gw + 1];
  float a0 = 0.f, a1 = 0.f;
  for (int i = s0; i < s1; i++){
    int s = csr[i];
    unsigned v = *(const unsigned*)(h + (size_t)s * D + lane * 2);
    a0 += bf2f((unsigned short)(v & 0xFFFFu));
    a1 += bf2f((unsigned short)(v >> 16));
  }
  int dgi = s1 - s0;
  float inv = 1.0f / (float)(dgi > 1 ? dgi : 1);
  a0 *= inv; a1 *= inv;
  unsigned pack = ((unsigned)f2bf(a1) << 16) | (unsigned)f2bf(a0);
  *(unsigned*)(out + (size_t)gw * D + lane * 2) = pack;
}

// ---- input layer: shortcut = x@sc_w.T + sc_b (fp32 into d_out);
//      h0 = gelu(x@dp_w.T + dp_b) (bf16 into hbuf) ----
__global__ __launch_bounds__(256) void k_in(const float* __restrict__ x,
    const unsigned short* __restrict__ wsc, const unsigned short* __restrict__ wdp,
    const float* __restrict__ scb, const float* __restrict__ dpb,
    float* __restrict__ shortcut, unsigned short* __restrict__ hbuf, int N){
  int tid = threadIdx.x;
  int w = tid >> 6, lane = tid & 63, quad = lane >> 4, l16 = lane & 15;
  int wr = w & 1, wc = w >> 1;
  int nb = blockIdx.x * 32 + wr * 16;
  int arow = min(nb + l16, N - 1);
  const unsigned short* W = wc ? wdp : wsc;
  f32x4 acc[8];
  #pragma unroll
  for (int t = 0; t < 8; t++) acc[t] = (f32x4){0.f, 0.f, 0.f, 0.f};
  #pragma unroll
  for (int k = 0; k < D; k += 32){
    int kk = k + quad * 8;
    const float* xp = x + (size_t)arow * D + kk;
    float4 xa = *(const float4*)xp;
    float4 xb = *(const float4*)(xp + 4);
    bf16x8 a;
    a[0] = (short)f2bf(xa.x); a[1] = (short)f2bf(xa.y);
    a[2] = (short)f2bf(xa.z); a[3] = (short)f2bf(xa.w);
    a[4] = (short)f2bf(xb.x); a[5] = (short)f2bf(xb.y);
    a[6] = (short)f2bf(xb.z); a[7] = (short)f2bf(xb.w);
    #pragma unroll
    for (int t = 0; t < 8; t++){
      bf16x8 b = *(const bf16x8*)(W + (size_t)(t * 16 + l16) * D + kk);
      acc[t] = __builtin_amdgcn_mfma_f32_16x16x32_bf16(a, b, acc[t], 0, 0, 0);
    }
  }
  const float* bias = wc ? dpb : scb;
  #pragma unroll
  for (int t = 0; t < 8; t++){
    int o = t * 16 + l16;
    float bv = bias[o];
    #pragma unroll
    for (int r = 0; r < 4; r++){
      int node = nb + quad * 4 + r;
      if (node < N){
        float v = acc[t][r] + bv;
        if (wc){
          hbuf[(size_t)node * D + o] = f2bf(gelu_exact(v));
        } else {
          shortcut[(size_t)node * D + o] = v;
        }
      }
    }
  }
}

// ---- SAGE layer: h = m@wl.T + lb + hin@wr.T ; LN ; (layer1: gelu->hbuf)
//      (layer2: gelu(.+shortcut) -> fp32 out, in-place with shortcut) ----
__global__ __launch_bounds__(256) void k_g(const unsigned short* hin,
    const unsigned short* __restrict__ mbuf,
    const unsigned short* __restrict__ wl, const unsigned short* __restrict__ wrr,
    const float* __restrict__ lb, const float* __restrict__ gamma,
    const float* __restrict__ beta,
    unsigned short* hout, float* fout, int N, int mode){
  __shared__ float tile[32][D + 1];
  __shared__ float reds[32][8];
  __shared__ float redq[32][8];
  __shared__ float mu_s[32], rs_s[32];
  int tid = threadIdx.x;
  int w = tid >> 6, lane = tid & 63, quad = lane >> 4, l16 = lane & 15;
  int wr = w & 1, wc = w >> 1;
  int nb0 = blockIdx.x * 32;
  int nb = nb0 + wr * 16;
  int arow = min(nb + l16, N - 1);
  f32x4 acc[4];
  #pragma unroll
  for (int t = 0; t < 4; t++) acc[t] = (f32x4){0.f, 0.f, 0.f, 0.f};
  #pragma unroll
  for (int k = 0; k < D; k += 32){
    int kk = k + quad * 8;
    bf16x8 am = *(const bf16x8*)(mbuf + (size_t)arow * D + kk);
    bf16x8 ah = *(const bf16x8*)(hin + (size_t)arow * D + kk);
    #pragma unroll
    for (int t = 0; t < 4; t++){
      int o = wc * 64 + t * 16 + l16;
      bf16x8 bl = *(const bf16x8*)(wl + (size_t)o * D + kk);
      bf16x8 br = *(const bf16x8*)(wrr + (size_t)o * D + kk);
      acc[t] = __builtin_amdgcn_mfma_f32_16x16x32_bf16(am, bl, acc[t], 0, 0, 0);
      acc[t] = __builtin_amdgcn_mfma_f32_16x16x32_bf16(ah, br, acc[t], 0, 0, 0);
    }
  }
  #pragma unroll
  for (int t = 0; t < 4; t++){
    int o = wc * 64 + t * 16 + l16;
    float bv = lb[o];
    #pragma unroll
    for (int r = 0; r < 4; r++){
      int nl = wr * 16 + quad * 4 + r;
      tile[nl][o] = acc[t][r] + bv;
    }
  }
  __syncthreads();
  int nl = tid >> 3, seg = tid & 7;
  float s = 0.f, s2 = 0.f;
  #pragma unroll
  for (int j = 0; j < 16; j++){
    float v = tile[nl][seg * 16 + j];
    s += v; s2 += v * v;
  }
  reds[nl][seg] = s; redq[nl][seg] = s2;
  __syncthreads();
  if (tid < 32){
    float ts = 0.f, tq = 0.f;
    #pragma unroll
    for (int j = 0; j < 8; j++){ ts += reds[tid][j]; tq += redq[tid][j]; }
    float mu = ts * (1.f / 128.f);
    float var = tq * (1.f / 128.f) - mu * mu;
    mu_s[tid] = mu;
    rs_s[tid] = rsqrtf(var + 1e-5f);
  }
  __syncthreads();
  int node = nb0 + nl;
  if (node < N){
    float mu = mu_s[nl], rs = rs_s[nl];
    if (mode == 0){
      #pragma unroll
      for (int j = 0; j < 16; j++){
        int o = seg * 16 + j;
        float v = (tile[nl][o] - mu) * rs * gamma[o] + beta[o];
        hout[(size_t)node * D + o] = f2bf(gelu_exact(v));
      }
    } else {
      #pragma unroll
      for (int j = 0; j < 16; j++){
        int o = seg * 16 + j;
        float v = (tile[nl][o] - mu) * rs * gamma[o] + beta[o];
        size_t idx = (size_t)node * D + o;
        fout[idx] = gelu_exact(v + fout[idx]);   // fout holds shortcut (fp32)
      }
    }
  }
}

extern "C" void kernel_launch(void* const* d_in, const int* in_sizes, int n_in,
                              void* d_out, int out_size, void* d_ws, size_t ws_size,
                              hipStream_t stream){
  const float* x     = (const float*)d_in[0];
  const int*   edges = (const int*)d_in[1];
  const float* dp_w  = (const float*)d_in[2];
  const float* dp_b  = (const float*)d_in[3];
  const float* sc_w  = (const float*)d_in[4];
  const float* sc_b  = (const float*)d_in[5];
  const float* g1_lw = (const float*)d_in[6];
  const float* g1_lb = (const float*)d_in[7];
  const float* g1_rw = (const float*)d_in[8];
  const float* n1_g  = (const float*)d_in[9];
  const float* n1_b  = (const float*)d_in[10];
  const float* g2_lw = (const float*)d_in[11];
  const float* g2_lb = (const float*)d_in[12];
  const float* g2_rw = (const float*)d_in[13];
  const float* n2_g  = (const float*)d_in[14];
  const float* n2_b  = (const float*)d_in[15];

  const int N = in_sizes[0] / D;
  const int E = in_sizes[1] / 2;
  const int* esrc = edges;
  const int* edst = edges + E;

  char* base = (char*)d_ws;
  size_t cur = 0;
  auto carve = [&](size_t b) -> char* {
    char* p = base + cur;
    cur = (cur + b + 255) & ~(size_t)255;
    return p;
  };
  int* off      = (int*)carve((size_t)(N + 1) * 4);
  int* run      = (int*)carve((size_t)N * 4);
  int* deg      = (int*)carve((size_t)N * 4);
  int* partials = (int*)carve(256 * 4);
  int* poff     = (int*)carve(256 * 4);
  int* csr      = (int*)carve((size_t)E * 4);
  unsigned short* wb   = (unsigned short*)carve((size_t)6 * 16384 * 2);
  unsigned short* hbuf = (unsigned short*)carve((size_t)N * D * 2);
  unsigned short* mbuf = (unsigned short*)carve((size_t)N * D * 2);

  unsigned short* wb_sc  = wb;
  unsigned short* wb_dp  = wb + 16384;
  unsigned short* wb_g1l = wb + 2 * 16384;
  unsigned short* wb_g1r = wb + 3 * 16384;
  unsigned short* wb_g2l = wb + 4 * 16384;
  unsigned short* wb_g2r = wb + 5 * 16384;

  float* out = (float*)d_out;

  hipMemsetAsync(deg, 0, (size_t)N * 4, stream);
  k_wcvt<<<dim3(64, 6), 256, 0, stream>>>(sc_w, dp_w, g1_lw, g1_rw, g2_lw, g2_rw, wb);
  k_hist<<<(E + 255) / 256, 256, 0, stream>>>(edst, deg, E);
  int nsb = (N + 1023) / 1024;
  k_scan1<<<nsb, 256, 0, stream>>>(deg, off, partials, N);
  k_scan2<<<1, 64, 0, stream>>>(partials, poff, nsb);
  k_scan3<<<(N + 255) / 256, 256, 0, stream>>>(off, run, poff, N, E);
  k_scatter<<<(E + 255) / 256, 256, 0, stream>>>(esrc, edst, run, csr, E);

  int ngb = (N + 31) / 32;
  k_in<<<ngb, 256, 0, stream>>>(x, wb_sc, wb_dp, sc_b, dp_b, out, hbuf, N);
  k_agg<<<(N + 3) / 4, 256, 0, stream>>>(hbuf, off, csr, mbuf, N);
  k_g<<<ngb, 256, 0, stream>>>(hbuf, mbuf, wb_g1l, wb_g1r, g1_lb, n1_g, n1_b,
                               hbuf, nullptr, N, 0);
  k_agg<<<(N + 3) / 4, 256, 0, stream>>>(hbuf, off, csr, mbuf, N);
  k_g<<<ngb, 256, 0, stream>>>(hbuf, mbuf, wb_g2l, wb_g2r, g2_lb, n2_g, n2_b,
                               nullptr, out, N, 1);
}

// Round 2
// 430.856 us; speedup vs baseline: 1.0942x; 1.0942x over previous
//
#include <hip/hip_runtime.h>
#include <hip/hip_bf16.h>
#include <math.h>

#define D 128
#define WS 136            // LDS row stride in shorts (128 + 8 pad, keeps 16B align)
#define FS 132            // LDS row stride in floats for fp32 tile (16B aligned)

typedef __attribute__((ext_vector_type(8))) short bf16x8;
typedef __attribute__((ext_vector_type(4))) float f32x4;

__device__ __forceinline__ unsigned short f2bf(float f){
  unsigned u = __float_as_uint(f);
  u = (u + 0x7FFFu + ((u >> 16) & 1u)) >> 16;
  return (unsigned short)u;
}
__device__ __forceinline__ float bf2f(unsigned short h){
  return __uint_as_float(((unsigned)h) << 16);
}
__device__ __forceinline__ float bf2f_lo(unsigned v){
  return __uint_as_float(v << 16);
}
__device__ __forceinline__ float bf2f_hi(unsigned v){
  return __uint_as_float(v & 0xFFFF0000u);
}
__device__ __forceinline__ float gelu_exact(float v){
  return 0.5f * v * (1.0f + erff(v * 0.70710678118654752f));
}

// ---- weights fp32 -> bf16 (6 matrices of 128x128) ----
__global__ void k_wcvt(const float* s0, const float* s1, const float* s2,
                       const float* s3, const float* s4, const float* s5,
                       unsigned short* dst){
  const float* srcs[6] = {s0, s1, s2, s3, s4, s5};
  int m = blockIdx.y;
  int i = blockIdx.x * 256 + threadIdx.x;
  dst[m * 16384 + i] = f2bf(srcs[m][i]);
}

// ---- CSR build ----
__global__ void k_hist(const int* __restrict__ dstn, int* __restrict__ deg, int E){
  int e = blockIdx.x * 256 + threadIdx.x;
  if (e < E) atomicAdd(&deg[dstn[e]], 1);
}

__global__ __launch_bounds__(256) void k_scan1(const int* __restrict__ deg,
                                               int* __restrict__ off,
                                               int* __restrict__ partials, int n){
  __shared__ int sm[256];
  int t = threadIdx.x;
  int base = blockIdx.x * 1024 + t * 4;
  int d[4];
  #pragma unroll
  for (int i = 0; i < 4; i++) d[i] = (base + i < n) ? deg[base + i] : 0;
  int s = d[0] + d[1] + d[2] + d[3];
  sm[t] = s; __syncthreads();
  for (int ofs = 1; ofs < 256; ofs <<= 1){
    int v = (t >= ofs) ? sm[t - ofs] : 0;
    __syncthreads();
    sm[t] += v;
    __syncthreads();
  }
  int run = sm[t] - s;
  #pragma unroll
  for (int i = 0; i < 4; i++){ if (base + i < n) off[base + i] = run; run += d[i]; }
  if (t == 255) partials[blockIdx.x] = sm[255];
}

__global__ void k_scan2(const int* __restrict__ partials, int* __restrict__ poff, int nb){
  __shared__ int sm[64];
  int t = threadIdx.x;
  int v = (t < nb) ? partials[t] : 0;
  sm[t] = v; __syncthreads();
  for (int ofs = 1; ofs < 64; ofs <<= 1){
    int u = (t >= ofs) ? sm[t - ofs] : 0;
    __syncthreads();
    sm[t] += u;
    __syncthreads();
  }
  if (t < nb) poff[t] = sm[t] - v;
}

__global__ void k_scan3(int* __restrict__ off, int* __restrict__ run,
                        const int* __restrict__ poff, int n, int E){
  int i = blockIdx.x * 256 + threadIdx.x;
  if (i < n){
    int v = off[i] + poff[i >> 10];
    off[i] = v; run[i] = v;
  }
  if (i == 0) off[n] = E;
}

__global__ void k_scatter(const int* __restrict__ srcn, const int* __restrict__ dstn,
                          int* __restrict__ run, int* __restrict__ csr, int E){
  int e = blockIdx.x * 256 + threadIdx.x;
  if (e < E){
    int pos = atomicAdd(&run[dstn[e]], 1);
    csr[pos] = srcn[e];
  }
}

// ---- mean aggregation: one wave per node, pipelined gather ----
__global__ __launch_bounds__(256) void k_agg(const unsigned short* __restrict__ h,
                                             const int* __restrict__ off,
                                             const int* __restrict__ csr,
                                             unsigned short* __restrict__ out, int N){
  int gw = (blockIdx.x * 256 + threadIdx.x) >> 6;
  int lane = threadIdx.x & 63;
  if (gw >= N) return;
  int s0 = off[gw], s1 = off[gw + 1];
  int cnt = s1 - s0;
  float a0 = 0.f, a1 = 0.f;
  for (int base = 0; base < cnt; base += 64){
    int take = cnt - base; if (take > 64) take = 64;
    int vidx = 0;
    if (lane < take) vidx = csr[s0 + base + lane];
    int i = 0;
    for (; i + 4 <= take; i += 4){
      int n0 = __shfl(vidx, i + 0);
      int n1 = __shfl(vidx, i + 1);
      int n2 = __shfl(vidx, i + 2);
      int n3 = __shfl(vidx, i + 3);
      unsigned v0 = *(const unsigned*)(h + (size_t)n0 * D + lane * 2);
      unsigned v1 = *(const unsigned*)(h + (size_t)n1 * D + lane * 2);
      unsigned v2 = *(const unsigned*)(h + (size_t)n2 * D + lane * 2);
      unsigned v3 = *(const unsigned*)(h + (size_t)n3 * D + lane * 2);
      a0 += bf2f_lo(v0) + bf2f_lo(v1) + bf2f_lo(v2) + bf2f_lo(v3);
      a1 += bf2f_hi(v0) + bf2f_hi(v1) + bf2f_hi(v2) + bf2f_hi(v3);
    }
    for (; i < take; i++){
      int n0 = __shfl(vidx, i);
      unsigned v0 = *(const unsigned*)(h + (size_t)n0 * D + lane * 2);
      a0 += bf2f_lo(v0);
      a1 += bf2f_hi(v0);
    }
  }
  float inv = 1.0f / (float)(cnt > 1 ? cnt : 1);
  a0 *= inv; a1 *= inv;
  unsigned pack = ((unsigned)f2bf(a1) << 16) | (unsigned)f2bf(a0);
  *(unsigned*)(out + (size_t)gw * D + lane * 2) = pack;
}

// ---- input layer: sbuf = bf16(x@sc_w.T + sc_b); hbuf = bf16(gelu(x@dp_w.T + dp_b))
//      block = 64 nodes; wave = 16 nodes x 256 outs (both matrices) ----
__global__ __launch_bounds__(256) void k_in(const float* __restrict__ x,
    const unsigned short* __restrict__ wsc, const unsigned short* __restrict__ wdp,
    const float* __restrict__ scb, const float* __restrict__ dpb,
    unsigned short* __restrict__ sbuf, unsigned short* __restrict__ hbuf, int N){
  __shared__ unsigned short sm[2 * 128 * WS];
  int tid = threadIdx.x;
  #pragma unroll
  for (int i = 0; i < 16; i++){
    int c = tid + 256 * i;          // 4096 chunks of 8 shorts
    int mat = c >> 11;
    int row = (c >> 4) & 127;
    int j = c & 15;
    const unsigned short* src = (mat ? wdp : wsc) + row * 128 + j * 8;
    *(bf16x8*)(sm + mat * 128 * WS + row * WS + j * 8) = *(const bf16x8*)src;
  }
  __syncthreads();
  int w = tid >> 6, lane = tid & 63, quad = lane >> 4, l16 = lane & 15;
  int nb0 = blockIdx.x * 64;
  int nb = nb0 + w * 16;
  int arow = min(nb + l16, N - 1);
  f32x4 acc[2][8];
  #pragma unroll
  for (int m = 0; m < 2; m++)
    #pragma unroll
    for (int t = 0; t < 8; t++) acc[m][t] = (f32x4){0.f, 0.f, 0.f, 0.f};
  #pragma unroll
  for (int k = 0; k < D; k += 32){
    int kk = k + quad * 8;
    float4 xa = *(const float4*)(x + (size_t)arow * D + kk);
    float4 xb = *(const float4*)(x + (size_t)arow * D + kk + 4);
    bf16x8 a;
    a[0] = (short)f2bf(xa.x); a[1] = (short)f2bf(xa.y);
    a[2] = (short)f2bf(xa.z); a[3] = (short)f2bf(xa.w);
    a[4] = (short)f2bf(xb.x); a[5] = (short)f2bf(xb.y);
    a[6] = (short)f2bf(xb.z); a[7] = (short)f2bf(xb.w);
    #pragma unroll
    for (int t = 0; t < 8; t++){
      bf16x8 b0 = *(const bf16x8*)(sm + (t * 16 + l16) * WS + kk);
      bf16x8 b1 = *(const bf16x8*)(sm + 128 * WS + (t * 16 + l16) * WS + kk);
      acc[0][t] = __builtin_amdgcn_mfma_f32_16x16x32_bf16(a, b0, acc[0][t], 0, 0, 0);
      acc[1][t] = __builtin_amdgcn_mfma_f32_16x16x32_bf16(a, b1, acc[1][t], 0, 0, 0);
    }
  }
  __syncthreads();   // weights done; reuse sm as output tile (64 x WS shorts)
  unsigned short* tile = sm;
  #pragma unroll
  for (int m = 0; m < 2; m++){
    const float* bias = m ? dpb : scb;
    #pragma unroll
    for (int t = 0; t < 8; t++){
      float bv = bias[t * 16 + l16];
      #pragma unroll
      for (int r = 0; r < 4; r++){
        int nl = w * 16 + quad * 4 + r;
        float v = acc[m][t][r] + bv;
        if (m) v = gelu_exact(v);
        tile[nl * WS + t * 16 + l16] = f2bf(v);
      }
    }
    __syncthreads();
    unsigned short* dst = m ? hbuf : sbuf;
    #pragma unroll
    for (int i = 0; i < 4; i++){
      int c = tid + 256 * i;        // 1024 chunks
      int nl = c >> 4, j = c & 15;
      int node = nb0 + nl;
      if (node < N)
        *(bf16x8*)(dst + (size_t)node * D + j * 8) = *(const bf16x8*)(tile + nl * WS + j * 8);
    }
    __syncthreads();
  }
}

// ---- SAGE layer: acc = mean@wl.T + lb + h@wr.T; LN; mode0: gelu->bf16 hout
//      mode1: gelu(LN + shortcut) -> fp32 fout. block = 128 nodes; wave = 32 nodes.
__global__ __launch_bounds__(256) void k_g(
    const unsigned short* __restrict__ hin, const unsigned short* __restrict__ mbuf,
    const unsigned short* __restrict__ wl, const unsigned short* __restrict__ wrr,
    const float* __restrict__ lb, const float* __restrict__ gamma,
    const float* __restrict__ beta,
    const unsigned short* __restrict__ sbuf,
    unsigned short* __restrict__ hout, float* __restrict__ fout, int N, int mode){
  __shared__ unsigned short sm[2 * 128 * WS];   // 69632 B
  int tid = threadIdx.x;
  #pragma unroll
  for (int i = 0; i < 16; i++){
    int c = tid + 256 * i;
    int mat = c >> 11;
    int row = (c >> 4) & 127;
    int j = c & 15;
    const unsigned short* src = (mat ? wrr : wl) + row * 128 + j * 8;
    *(bf16x8*)(sm + mat * 128 * WS + row * WS + j * 8) = *(const bf16x8*)src;
  }
  __syncthreads();
  int w = tid >> 6, lane = tid & 63, quad = lane >> 4, l16 = lane & 15;
  int nb0 = blockIdx.x * 128;
  int nb = nb0 + w * 32;
  int r0 = min(nb + l16, N - 1);
  int r1 = min(nb + 16 + l16, N - 1);
  f32x4 acc[2][8];
  #pragma unroll
  for (int p = 0; p < 2; p++)
    #pragma unroll
    for (int t = 0; t < 8; t++) acc[p][t] = (f32x4){0.f, 0.f, 0.f, 0.f};
  #pragma unroll
  for (int k = 0; k < D; k += 32){
    int kk = k + quad * 8;
    bf16x8 am0 = *(const bf16x8*)(mbuf + (size_t)r0 * D + kk);
    bf16x8 ah0 = *(const bf16x8*)(hin + (size_t)r0 * D + kk);
    bf16x8 am1 = *(const bf16x8*)(mbuf + (size_t)r1 * D + kk);
    bf16x8 ah1 = *(const bf16x8*)(hin + (size_t)r1 * D + kk);
    #pragma unroll
    for (int t = 0; t < 8; t++){
      bf16x8 bl = *(const bf16x8*)(sm + (t * 16 + l16) * WS + kk);
      bf16x8 br = *(const bf16x8*)(sm + 128 * WS + (t * 16 + l16) * WS + kk);
      acc[0][t] = __builtin_amdgcn_mfma_f32_16x16x32_bf16(am0, bl, acc[0][t], 0, 0, 0);
      acc[0][t] = __builtin_amdgcn_mfma_f32_16x16x32_bf16(ah0, br, acc[0][t], 0, 0, 0);
      acc[1][t] = __builtin_amdgcn_mfma_f32_16x16x32_bf16(am1, bl, acc[1][t], 0, 0, 0);
      acc[1][t] = __builtin_amdgcn_mfma_f32_16x16x32_bf16(ah1, br, acc[1][t], 0, 0, 0);
    }
  }
  // bias + LayerNorm stats (in-register, 16-lane shuffle reduction)
  float lbv[8], gv[8], bv[8];
  #pragma unroll
  for (int t = 0; t < 8; t++){
    lbv[t] = lb[t * 16 + l16];
    gv[t] = gamma[t * 16 + l16];
    bv[t] = beta[t * 16 + l16];
  }
  float mu[2][4], rs[2][4];
  #pragma unroll
  for (int p = 0; p < 2; p++){
    #pragma unroll
    for (int r = 0; r < 4; r++){
      float s = 0.f, q = 0.f;
      #pragma unroll
      for (int t = 0; t < 8; t++){
        float v = acc[p][t][r] + lbv[t];
        acc[p][t][r] = v;
        s += v; q += v * v;
      }
      s += __shfl_xor(s, 1); q += __shfl_xor(q, 1);
      s += __shfl_xor(s, 2); q += __shfl_xor(q, 2);
      s += __shfl_xor(s, 4); q += __shfl_xor(q, 4);
      s += __shfl_xor(s, 8); q += __shfl_xor(q, 8);
      float m_ = s * (1.f / 128.f);
      mu[p][r] = m_;
      rs[p][r] = rsqrtf(q * (1.f / 128.f) - m_ * m_ + 1e-5f);
    }
  }
  __syncthreads();   // weights done; reuse sm
  if (mode == 0){
    unsigned short* tile = sm;    // 128 x WS shorts
    #pragma unroll
    for (int p = 0; p < 2; p++)
      #pragma unroll
      for (int t = 0; t < 8; t++)
        #pragma unroll
        for (int r = 0; r < 4; r++){
          int nl = w * 32 + p * 16 + quad * 4 + r;
          float v = (acc[p][t][r] - mu[p][r]) * rs[p][r] * gv[t] + bv[t];
          tile[nl * WS + t * 16 + l16] = f2bf(gelu_exact(v));
        }
    __syncthreads();
    #pragma unroll
    for (int i = 0; i < 8; i++){
      int c = tid + 256 * i;        // 2048 chunks
      int nl = c >> 4, j = c & 15;
      int node = nb0 + nl;
      if (node < N)
        *(bf16x8*)(hout + (size_t)node * D + j * 8) = *(const bf16x8*)(tile + nl * WS + j * 8);
    }
  } else {
    // stage shortcut tile (coalesced) then consume in C-layout
    unsigned short* stile = sm;
    #pragma unroll
    for (int i = 0; i < 8; i++){
      int c = tid + 256 * i;
      int nl = c >> 4, j = c & 15;
      int node = nb0 + nl;
      bf16x8 v = (bf16x8){0,0,0,0,0,0,0,0};
      if (node < N) v = *(const bf16x8*)(sbuf + (size_t)node * D + j * 8);
      *(bf16x8*)(stile + nl * WS + j * 8) = v;
    }
    __syncthreads();
    #pragma unroll
    for (int p = 0; p < 2; p++)
      #pragma unroll
      for (int t = 0; t < 8; t++)
        #pragma unroll
        for (int r = 0; r < 4; r++){
          int nl = w * 32 + p * 16 + quad * 4 + r;
          float sc = bf2f(stile[nl * WS + t * 16 + l16]);
          float v = (acc[p][t][r] - mu[p][r]) * rs[p][r] * gv[t] + bv[t];
          acc[p][t][r] = gelu_exact(v + sc);
        }
    __syncthreads();
    float* ftile = (float*)sm;    // 128 x FS floats = 67584 B
    #pragma unroll
    for (int p = 0; p < 2; p++)
      #pragma unroll
      for (int t = 0; t < 8; t++)
        #pragma unroll
        for (int r = 0; r < 4; r++){
          int nl = w * 32 + p * 16 + quad * 4 + r;
          ftile[nl * FS + t * 16 + l16] = acc[p][t][r];
        }
    __syncthreads();
    #pragma unroll
    for (int i = 0; i < 16; i++){
      int c = tid + 256 * i;        // 4096 chunks of 4 floats
      int nl = c >> 5, j = c & 31;
      int node = nb0 + nl;
      if (node < N)
        *(float4*)(fout + (size_t)node * D + j * 4) = *(const float4*)(ftile + nl * FS + j * 4);
    }
  }
}

extern "C" void kernel_launch(void* const* d_in, const int* in_sizes, int n_in,
                              void* d_out, int out_size, void* d_ws, size_t ws_size,
                              hipStream_t stream){
  const float* x     = (const float*)d_in[0];
  const int*   edges = (const int*)d_in[1];
  const float* dp_w  = (const float*)d_in[2];
  const float* dp_b  = (const float*)d_in[3];
  const float* sc_w  = (const float*)d_in[4];
  const float* sc_b  = (const float*)d_in[5];
  const float* g1_lw = (const float*)d_in[6];
  const float* g1_lb = (const float*)d_in[7];
  const float* g1_rw = (const float*)d_in[8];
  const float* n1_g  = (const float*)d_in[9];
  const float* n1_b  = (const float*)d_in[10];
  const float* g2_lw = (const float*)d_in[11];
  const float* g2_lb = (const float*)d_in[12];
  const float* g2_rw = (const float*)d_in[13];
  const float* n2_g  = (const float*)d_in[14];
  const float* n2_b  = (const float*)d_in[15];

  const int N = in_sizes[0] / D;
  const int E = in_sizes[1] / 2;
  const int* esrc = edges;
  const int* edst = edges + E;

  char* base = (char*)d_ws;
  size_t cur = 0;
  auto carve = [&](size_t b) -> char* {
    char* p = base + cur;
    cur = (cur + b + 255) & ~(size_t)255;
    return p;
  };
  int* off      = (int*)carve((size_t)(N + 1) * 4);
  int* run      = (int*)carve((size_t)N * 4);
  int* deg      = (int*)carve((size_t)N * 4);
  int* partials = (int*)carve(256 * 4);
  int* poff     = (int*)carve(256 * 4);
  int* csr      = (int*)carve((size_t)E * 4);
  unsigned short* wb   = (unsigned short*)carve((size_t)6 * 16384 * 2);
  unsigned short* hbuf = (unsigned short*)carve((size_t)N * D * 2);
  unsigned short* mbuf = (unsigned short*)carve((size_t)N * D * 2);
  unsigned short* sbuf = (unsigned short*)carve((size_t)N * D * 2);

  unsigned short* wb_sc  = wb;
  unsigned short* wb_dp  = wb + 16384;
  unsigned short* wb_g1l = wb + 2 * 16384;
  unsigned short* wb_g1r = wb + 3 * 16384;
  unsigned short* wb_g2l = wb + 4 * 16384;
  unsigned short* wb_g2r = wb + 5 * 16384;

  float* out = (float*)d_out;

  hipMemsetAsync(deg, 0, (size_t)N * 4, stream);
  k_wcvt<<<dim3(64, 6), 256, 0, stream>>>(sc_w, dp_w, g1_lw, g1_rw, g2_lw, g2_rw, wb);
  k_hist<<<(E + 255) / 256, 256, 0, stream>>>(edst, deg, E);
  int nsb = (N + 1023) / 1024;
  k_scan1<<<nsb, 256, 0, stream>>>(deg, off, partials, N);
  k_scan2<<<1, 64, 0, stream>>>(partials, poff, nsb);
  k_scan3<<<(N + 255) / 256, 256, 0, stream>>>(off, run, poff, N, E);
  k_scatter<<<(E + 255) / 256, 256, 0, stream>>>(esrc, edst, run, csr, E);

  k_in<<<(N + 63) / 64, 256, 0, stream>>>(x, wb_sc, wb_dp, sc_b, dp_b, sbuf, hbuf, N);
  k_agg<<<(N + 3) / 4, 256, 0, stream>>>(hbuf, off, csr, mbuf, N);
  k_g<<<(N + 127) / 128, 256, 0, stream>>>(hbuf, mbuf, wb_g1l, wb_g1r, g1_lb, n1_g, n1_b,
                                           nullptr, hbuf, nullptr, N, 0);
  k_agg<<<(N + 3) / 4, 256, 0, stream>>>(hbuf, off, csr, mbuf, N);
  k_g<<<(N + 127) / 128, 256, 0, stream>>>(hbuf, mbuf, wb_g2l, wb_g2r, g2_lb, n2_g, n2_b,
                                           sbuf, nullptr, out, N, 1);
}

// Round 3
// 299.317 us; speedup vs baseline: 1.5751x; 1.4395x over previous
//
#include <hip/hip_runtime.h>
#include <hip/hip_bf16.h>
#include <math.h>

#define D 128
#define WS 136            // LDS row stride in shorts (128 + 8 pad)
#define FS 132            // LDS row stride in floats

typedef __attribute__((ext_vector_type(8))) short bf16x8;
typedef __attribute__((ext_vector_type(4))) float f32x4;

__device__ __forceinline__ unsigned short f2bf(float f){
  unsigned u = __float_as_uint(f);
  u = (u + 0x7FFFu + ((u >> 16) & 1u)) >> 16;
  return (unsigned short)u;
}
__device__ __forceinline__ float bf2f(unsigned short h){
  return __uint_as_float(((unsigned)h) << 16);
}
__device__ __forceinline__ float bf2f_lo(unsigned v){
  return __uint_as_float(v << 16);
}
__device__ __forceinline__ float bf2f_hi(unsigned v){
  return __uint_as_float(v & 0xFFFF0000u);
}
// tanh-form gelu: max |err| vs exact ~3e-3, ~7 VALU ops
__device__ __forceinline__ float gelu_fast(float v){
  float u = v * v;
  float arg = v * (1.5957691216f + 0.0713548163f * u);
  arg = fminf(arg, 60.0f);
  float e = __expf(arg);
  return v * e * __builtin_amdgcn_rcpf(e + 1.0f);
}

// ---- weights fp32 -> bf16 frag-major: dst[mat][((kk*8+t)*64+lane)*8+j] =
//      W[t*16+(lane&15)][kk*32+(lane>>4)*8+j] ----
__global__ __launch_bounds__(64) void k_wcvt(const float* s0, const float* s1,
    const float* s2, const float* s3, const float* s4, const float* s5,
    unsigned short* dst){
  const float* srcs[6] = {s0, s1, s2, s3, s4, s5};
  int f = blockIdx.x;          // 0..31
  int m = blockIdx.y;          // 0..5
  int lane = threadIdx.x;
  int t = f & 7, kk = f >> 3;
  int row = t * 16 + (lane & 15);
  int col = kk * 32 + (lane >> 4) * 8;
  const float* src = srcs[m] + row * 128 + col;
  float4 a = *(const float4*)src;
  float4 b = *(const float4*)(src + 4);
  bf16x8 o;
  o[0] = (short)f2bf(a.x); o[1] = (short)f2bf(a.y);
  o[2] = (short)f2bf(a.z); o[3] = (short)f2bf(a.w);
  o[4] = (short)f2bf(b.x); o[5] = (short)f2bf(b.y);
  o[6] = (short)f2bf(b.z); o[7] = (short)f2bf(b.w);
  *(bf16x8*)(dst + (size_t)m * 16384 + ((size_t)f * 64 + lane) * 8) = o;
}

// ---- CSR build ----
__global__ void k_hist(const int* __restrict__ dstn, int* __restrict__ deg, int E){
  int e = blockIdx.x * 256 + threadIdx.x;
  if (e < E) atomicAdd(&deg[dstn[e]], 1);
}

__global__ __launch_bounds__(256) void k_scan1(const int* __restrict__ deg,
                                               int* __restrict__ off,
                                               int* __restrict__ partials, int n){
  __shared__ int sm[256];
  int t = threadIdx.x;
  int base = blockIdx.x * 1024 + t * 4;
  int d[4];
  #pragma unroll
  for (int i = 0; i < 4; i++) d[i] = (base + i < n) ? deg[base + i] : 0;
  int s = d[0] + d[1] + d[2] + d[3];
  sm[t] = s; __syncthreads();
  for (int ofs = 1; ofs < 256; ofs <<= 1){
    int v = (t >= ofs) ? sm[t - ofs] : 0;
    __syncthreads();
    sm[t] += v;
    __syncthreads();
  }
  int run = sm[t] - s;
  #pragma unroll
  for (int i = 0; i < 4; i++){ if (base + i < n) off[base + i] = run; run += d[i]; }
  if (t == 255) partials[blockIdx.x] = sm[255];
}

__global__ void k_scan2(const int* __restrict__ partials, int* __restrict__ poff, int nb){
  __shared__ int sm[64];
  int t = threadIdx.x;
  int v = (t < nb) ? partials[t] : 0;
  sm[t] = v; __syncthreads();
  for (int ofs = 1; ofs < 64; ofs <<= 1){
    int u = (t >= ofs) ? sm[t - ofs] : 0;
    __syncthreads();
    sm[t] += u;
    __syncthreads();
  }
  if (t < nb) poff[t] = sm[t] - v;
}

__global__ void k_scan3(int* __restrict__ off, int* __restrict__ run,
                        const int* __restrict__ poff, int n, int E){
  int i = blockIdx.x * 256 + threadIdx.x;
  if (i < n){
    int v = off[i] + poff[i >> 10];
    off[i] = v; run[i] = v;
  }
  if (i == 0) off[n] = E;
}

__global__ void k_scatter(const int* __restrict__ srcn, const int* __restrict__ dstn,
                          int* __restrict__ run, int* __restrict__ csr, int E){
  int e = blockIdx.x * 256 + threadIdx.x;
  if (e < E){
    int pos = atomicAdd(&run[dstn[e]], 1);
    csr[pos] = srcn[e];
  }
}

// ---- mean aggregation: one wave per node, 8-deep MLP gather ----
__global__ __launch_bounds__(256) void k_agg(const unsigned short* __restrict__ h,
                                             const int* __restrict__ off,
                                             const int* __restrict__ csr,
                                             unsigned short* __restrict__ out, int N){
  int gw = (blockIdx.x * 256 + threadIdx.x) >> 6;
  int lane = threadIdx.x & 63;
  if (gw >= N) return;
  int s0 = off[gw], s1 = off[gw + 1];
  int cnt = s1 - s0;
  float a0 = 0.f, a1 = 0.f;
  for (int base = 0; base < cnt; base += 64){
    int take = cnt - base; if (take > 64) take = 64;
    int vidx = 0;
    if (lane < take) vidx = csr[s0 + base + lane];
    int i = 0;
    for (; i + 8 <= take; i += 8){
      unsigned v[8];
      #pragma unroll
      for (int j = 0; j < 8; j++){
        int nj = __shfl(vidx, i + j);
        v[j] = *(const unsigned*)(h + (size_t)nj * D + lane * 2);
      }
      #pragma unroll
      for (int j = 0; j < 8; j++){
        a0 += bf2f_lo(v[j]);
        a1 += bf2f_hi(v[j]);
      }
    }
    for (; i < take; i++){
      int nj = __shfl(vidx, i);
      unsigned v0 = *(const unsigned*)(h + (size_t)nj * D + lane * 2);
      a0 += bf2f_lo(v0);
      a1 += bf2f_hi(v0);
    }
  }
  float inv = 1.0f / (float)(cnt > 1 ? cnt : 1);
  a0 *= inv; a1 *= inv;
  unsigned pack = ((unsigned)f2bf(a1) << 16) | (unsigned)f2bf(a0);
  *(unsigned*)(out + (size_t)gw * D + lane * 2) = pack;
}

// ---- input layer: one wave per 16 nodes; 256 outs (sc then dp) ----
__global__ __launch_bounds__(64) void k_in(const float* __restrict__ x,
    const unsigned short* __restrict__ wsc, const unsigned short* __restrict__ wdp,
    const float* __restrict__ scb, const float* __restrict__ dpb,
    unsigned short* __restrict__ sbuf, unsigned short* __restrict__ hbuf, int N){
  __shared__ unsigned short tile[16 * WS];
  int lane = threadIdx.x, quad = lane >> 4, l16 = lane & 15;
  int nb = blockIdx.x * 16;
  int arow = min(nb + l16, N - 1);
  f32x4 acc[2][8];
  #pragma unroll
  for (int m = 0; m < 2; m++)
    #pragma unroll
    for (int t = 0; t < 8; t++) acc[m][t] = (f32x4){0.f, 0.f, 0.f, 0.f};
  #pragma unroll
  for (int kk = 0; kk < 4; kk++){
    const float* xp = x + (size_t)arow * D + kk * 32 + quad * 8;
    float4 xa = *(const float4*)xp;
    float4 xb = *(const float4*)(xp + 4);
    bf16x8 a;
    a[0] = (short)f2bf(xa.x); a[1] = (short)f2bf(xa.y);
    a[2] = (short)f2bf(xa.z); a[3] = (short)f2bf(xa.w);
    a[4] = (short)f2bf(xb.x); a[5] = (short)f2bf(xb.y);
    a[6] = (short)f2bf(xb.z); a[7] = (short)f2bf(xb.w);
    #pragma unroll
    for (int t = 0; t < 8; t++){
      size_t fo = ((size_t)(kk * 8 + t) * 64 + lane) * 8;
      bf16x8 b0 = *(const bf16x8*)(wsc + fo);
      bf16x8 b1 = *(const bf16x8*)(wdp + fo);
      acc[0][t] = __builtin_amdgcn_mfma_f32_16x16x32_bf16(a, b0, acc[0][t], 0, 0, 0);
      acc[1][t] = __builtin_amdgcn_mfma_f32_16x16x32_bf16(a, b1, acc[1][t], 0, 0, 0);
    }
  }
  #pragma unroll
  for (int m = 0; m < 2; m++){
    const float* bias = m ? dpb : scb;
    #pragma unroll
    for (int t = 0; t < 8; t++){
      float bv = bias[t * 16 + l16];
      #pragma unroll
      for (int r = 0; r < 4; r++){
        float v = acc[m][t][r] + bv;
        if (m) v = gelu_fast(v);
        tile[(quad * 4 + r) * WS + t * 16 + l16] = f2bf(v);
      }
    }
    __syncthreads();
    unsigned short* dst = m ? hbuf : sbuf;
    #pragma unroll
    for (int i = 0; i < 4; i++){
      int c = lane + 64 * i;          // 256 chunks of 8 shorts
      int nl = c >> 4, j = c & 15;
      int node = nb + nl;
      if (node < N)
        *(bf16x8*)(dst + (size_t)node * D + j * 8) = *(const bf16x8*)(tile + nl * WS + j * 8);
    }
    __syncthreads();
  }
}

// ---- SAGE layer: one wave per 32 nodes; acc = mean@wl.T + lb + h@wr.T; LN;
//      mode0: gelu -> bf16 hout; mode1: gelu(LN + shortcut) -> fp32 fout ----
__global__ __launch_bounds__(64) void k_g(
    const unsigned short* __restrict__ hin, const unsigned short* __restrict__ mbuf,
    const unsigned short* __restrict__ wl, const unsigned short* __restrict__ wrr,
    const float* __restrict__ lb, const float* __restrict__ gamma,
    const float* __restrict__ beta,
    const unsigned short* __restrict__ sbuf,
    unsigned short* __restrict__ hout, float* __restrict__ fout, int N, int mode){
  __shared__ char smraw[32 * FS * 4];      // 16.9KB, unioned
  unsigned short* stile = (unsigned short*)smraw;   // 32 x WS shorts
  float* ftile = (float*)smraw;                     // 32 x FS floats
  int lane = threadIdx.x, quad = lane >> 4, l16 = lane & 15;
  int nb = blockIdx.x * 32;
  int r0 = min(nb + l16, N - 1);
  int r1 = min(nb + 16 + l16, N - 1);
  f32x4 acc[2][8];
  #pragma unroll
  for (int p = 0; p < 2; p++)
    #pragma unroll
    for (int t = 0; t < 8; t++) acc[p][t] = (f32x4){0.f, 0.f, 0.f, 0.f};
  #pragma unroll
  for (int kk = 0; kk < 4; kk++){
    int co = kk * 32 + quad * 8;
    bf16x8 am0 = *(const bf16x8*)(mbuf + (size_t)r0 * D + co);
    bf16x8 ah0 = *(const bf16x8*)(hin + (size_t)r0 * D + co);
    bf16x8 am1 = *(const bf16x8*)(mbuf + (size_t)r1 * D + co);
    bf16x8 ah1 = *(const bf16x8*)(hin + (size_t)r1 * D + co);
    #pragma unroll
    for (int t = 0; t < 8; t++){
      size_t fo = ((size_t)(kk * 8 + t) * 64 + lane) * 8;
      bf16x8 bl = *(const bf16x8*)(wl + fo);
      bf16x8 br = *(const bf16x8*)(wrr + fo);
      acc[0][t] = __builtin_amdgcn_mfma_f32_16x16x32_bf16(am0, bl, acc[0][t], 0, 0, 0);
      acc[0][t] = __builtin_amdgcn_mfma_f32_16x16x32_bf16(ah0, br, acc[0][t], 0, 0, 0);
      acc[1][t] = __builtin_amdgcn_mfma_f32_16x16x32_bf16(am1, bl, acc[1][t], 0, 0, 0);
      acc[1][t] = __builtin_amdgcn_mfma_f32_16x16x32_bf16(ah1, br, acc[1][t], 0, 0, 0);
    }
  }
  // bias + LN stats in-register (16-lane shuffle reduction)
  float lbv[8], gv[8], bv[8];
  #pragma unroll
  for (int t = 0; t < 8; t++){
    lbv[t] = lb[t * 16 + l16];
    gv[t] = gamma[t * 16 + l16];
    bv[t] = beta[t * 16 + l16];
  }
  float mu[2][4], rs[2][4];
  #pragma unroll
  for (int p = 0; p < 2; p++){
    #pragma unroll
    for (int r = 0; r < 4; r++){
      float s = 0.f, q = 0.f;
      #pragma unroll
      for (int t = 0; t < 8; t++){
        float v = acc[p][t][r] + lbv[t];
        acc[p][t][r] = v;
        s += v; q += v * v;
      }
      s += __shfl_xor(s, 1); q += __shfl_xor(q, 1);
      s += __shfl_xor(s, 2); q += __shfl_xor(q, 2);
      s += __shfl_xor(s, 4); q += __shfl_xor(q, 4);
      s += __shfl_xor(s, 8); q += __shfl_xor(q, 8);
      float m_ = s * (1.f / 128.f);
      mu[p][r] = m_;
      rs[p][r] = rsqrtf(q * (1.f / 128.f) - m_ * m_ + 1e-5f);
    }
  }
  if (mode == 0){
    #pragma unroll
    for (int p = 0; p < 2; p++)
      #pragma unroll
      for (int t = 0; t < 8; t++)
        #pragma unroll
        for (int r = 0; r < 4; r++){
          int nl = p * 16 + quad * 4 + r;
          float v = (acc[p][t][r] - mu[p][r]) * rs[p][r] * gv[t] + bv[t];
          stile[nl * WS + t * 16 + l16] = f2bf(gelu_fast(v));
        }
    __syncthreads();
    #pragma unroll
    for (int i = 0; i < 8; i++){
      int c = lane + 64 * i;          // 512 chunks of 8 shorts
      int nl = c >> 4, j = c & 15;
      int node = nb + nl;
      if (node < N)
        *(bf16x8*)(hout + (size_t)node * D + j * 8) = *(const bf16x8*)(stile + nl * WS + j * 8);
    }
  } else {
    // stage shortcut (coalesced in), consume in C-layout
    #pragma unroll
    for (int i = 0; i < 8; i++){
      int c = lane + 64 * i;
      int nl = c >> 4, j = c & 15;
      int node = nb + nl;
      bf16x8 v = (bf16x8){0,0,0,0,0,0,0,0};
      if (node < N) v = *(const bf16x8*)(sbuf + (size_t)node * D + j * 8);
      *(bf16x8*)(stile + nl * WS + j * 8) = v;
    }
    __syncthreads();
    float sc[2][8][4];
    #pragma unroll
    for (int p = 0; p < 2; p++)
      #pragma unroll
      for (int t = 0; t < 8; t++)
        #pragma unroll
        for (int r = 0; r < 4; r++){
          int nl = p * 16 + quad * 4 + r;
          sc[p][t][r] = bf2f(stile[nl * WS + t * 16 + l16]);
        }
    __syncthreads();
    #pragma unroll
    for (int p = 0; p < 2; p++)
      #pragma unroll
      for (int t = 0; t < 8; t++)
        #pragma unroll
        for (int r = 0; r < 4; r++){
          int nl = p * 16 + quad * 4 + r;
          float v = (acc[p][t][r] - mu[p][r]) * rs[p][r] * gv[t] + bv[t];
          ftile[nl * FS + t * 16 + l16] = gelu_fast(v + sc[p][t][r]);
        }
    __syncthreads();
    #pragma unroll
    for (int i = 0; i < 16; i++){
      int c = lane + 64 * i;          // 1024 chunks of 4 floats
      int nl = c >> 5, j = c & 31;
      int node = nb + nl;
      if (node < N)
        *(float4*)(fout + (size_t)node * D + j * 4) = *(const float4*)(ftile + nl * FS + j * 4);
    }
  }
}

extern "C" void kernel_launch(void* const* d_in, const int* in_sizes, int n_in,
                              void* d_out, int out_size, void* d_ws, size_t ws_size,
                              hipStream_t stream){
  const float* x     = (const float*)d_in[0];
  const int*   edges = (const int*)d_in[1];
  const float* dp_w  = (const float*)d_in[2];
  const float* dp_b  = (const float*)d_in[3];
  const float* sc_w  = (const float*)d_in[4];
  const float* sc_b  = (const float*)d_in[5];
  const float* g1_lw = (const float*)d_in[6];
  const float* g1_lb = (const float*)d_in[7];
  const float* g1_rw = (const float*)d_in[8];
  const float* n1_g  = (const float*)d_in[9];
  const float* n1_b  = (const float*)d_in[10];
  const float* g2_lw = (const float*)d_in[11];
  const float* g2_lb = (const float*)d_in[12];
  const float* g2_rw = (const float*)d_in[13];
  const float* n2_g  = (const float*)d_in[14];
  const float* n2_b  = (const float*)d_in[15];

  const int N = in_sizes[0] / D;
  const int E = in_sizes[1] / 2;
  const int* esrc = edges;
  const int* edst = edges + E;

  char* base = (char*)d_ws;
  size_t cur = 0;
  auto carve = [&](size_t b) -> char* {
    char* p = base + cur;
    cur = (cur + b + 255) & ~(size_t)255;
    return p;
  };
  int* off      = (int*)carve((size_t)(N + 1) * 4);
  int* run      = (int*)carve((size_t)N * 4);
  int* deg      = (int*)carve((size_t)N * 4);
  int* partials = (int*)carve(256 * 4);
  int* poff     = (int*)carve(256 * 4);
  int* csr      = (int*)carve((size_t)E * 4);
  unsigned short* wb   = (unsigned short*)carve((size_t)6 * 16384 * 2);
  unsigned short* hbuf = (unsigned short*)carve((size_t)N * D * 2);
  unsigned short* mbuf = (unsigned short*)carve((size_t)N * D * 2);
  unsigned short* sbuf = (unsigned short*)carve((size_t)N * D * 2);

  unsigned short* wb_sc  = wb;
  unsigned short* wb_dp  = wb + 16384;
  unsigned short* wb_g1l = wb + 2 * 16384;
  unsigned short* wb_g1r = wb + 3 * 16384;
  unsigned short* wb_g2l = wb + 4 * 16384;
  unsigned short* wb_g2r = wb + 5 * 16384;

  float* out = (float*)d_out;

  hipMemsetAsync(deg, 0, (size_t)N * 4, stream);
  k_wcvt<<<dim3(32, 6), 64, 0, stream>>>(sc_w, dp_w, g1_lw, g1_rw, g2_lw, g2_rw, wb);
  k_hist<<<(E + 255) / 256, 256, 0, stream>>>(edst, deg, E);
  int nsb = (N + 1023) / 1024;
  k_scan1<<<nsb, 256, 0, stream>>>(deg, off, partials, N);
  k_scan2<<<1, 64, 0, stream>>>(partials, poff, nsb);
  k_scan3<<<(N + 255) / 256, 256, 0, stream>>>(off, run, poff, N, E);
  k_scatter<<<(E + 255) / 256, 256, 0, stream>>>(esrc, edst, run, csr, E);

  k_in<<<(N + 15) / 16, 64, 0, stream>>>(x, wb_sc, wb_dp, sc_b, dp_b, sbuf, hbuf, N);
  k_agg<<<(N + 3) / 4, 256, 0, stream>>>(hbuf, off, csr, mbuf, N);
  k_g<<<(N + 31) / 32, 64, 0, stream>>>(hbuf, mbuf, wb_g1l, wb_g1r, g1_lb, n1_g, n1_b,
                                        nullptr, hbuf, nullptr, N, 0);
  k_agg<<<(N + 3) / 4, 256, 0, stream>>>(hbuf, off, csr, mbuf, N);
  k_g<<<(N + 31) / 32, 64, 0, stream>>>(hbuf, mbuf, wb_g2l, wb_g2r, g2_lb, n2_g, n2_b,
                                        sbuf, nullptr, out, N, 1);
}

// Round 4
// 279.045 us; speedup vs baseline: 1.6895x; 1.0727x over previous
//
#include <hip/hip_runtime.h>
#include <hip/hip_bf16.h>
#include <math.h>

#define D 128
#define WS 136            // LDS row stride in shorts
#define FS 132            // LDS row stride in floats

typedef __attribute__((ext_vector_type(8))) short bf16x8;
typedef __attribute__((ext_vector_type(4))) float f32x4;

__device__ __forceinline__ unsigned short f2bf(float f){
  return (unsigned short)((__float_as_uint(f) + 0x8000u) >> 16);
}
__device__ __forceinline__ float bf2f(unsigned short h){
  return __uint_as_float(((unsigned)h) << 16);
}
__device__ __forceinline__ float bf2f_lo(unsigned v){
  return __uint_as_float(v << 16);
}
__device__ __forceinline__ float bf2f_hi(unsigned v){
  return __uint_as_float(v & 0xFFFF0000u);
}
__device__ __forceinline__ float gelu_fast(float v){
  float u = v * v;
  float arg = v * (1.5957691216f + 0.0713548163f * u);
  arg = fminf(arg, 60.0f);
  float e = __expf(arg);
  return v * e * __builtin_amdgcn_rcpf(e + 1.0f);
}

// ---- prep: weights fp32 -> bf16 frag-major pair-interleaved; zero deg ----
// pair layout: dst[pair][ ((f*2+half)*64 + lane)*8 ], f = kk*8+t
// pairs: 0=(sc,dp), 1=(g1l,g1r), 2=(g2l,g2r)
__global__ __launch_bounds__(256) void k_prep(const float* s0, const float* s1,
    const float* s2, const float* s3, const float* s4, const float* s5,
    unsigned short* dst, int* deg, int N, int nwb){
  int b = blockIdx.x;
  if (b < nwb){
    int gt = b * 256 + threadIdx.x;      // 0..12287
    int m = gt >> 11;                    // matrix 0..5 (uniform per block)
    int r = gt & 2047;
    int f = r >> 6, lane = r & 63;
    int t = f & 7, kk = f >> 3;
    int row = t * 16 + (lane & 15);
    int col = kk * 32 + (lane >> 4) * 8;
    const float* src;
    if (m == 0) src = s0; else if (m == 1) src = s1; else if (m == 2) src = s2;
    else if (m == 3) src = s3; else if (m == 4) src = s4; else src = s5;
    src += row * 128 + col;
    float4 a = *(const float4*)src;
    float4 bb = *(const float4*)(src + 4);
    bf16x8 o;
    o[0] = (short)f2bf(a.x);  o[1] = (short)f2bf(a.y);
    o[2] = (short)f2bf(a.z);  o[3] = (short)f2bf(a.w);
    o[4] = (short)f2bf(bb.x); o[5] = (short)f2bf(bb.y);
    o[6] = (short)f2bf(bb.z); o[7] = (short)f2bf(bb.w);
    int pair = m >> 1, half = m & 1;
    *(bf16x8*)(dst + (size_t)pair * 32768 + (((size_t)f * 2 + half) * 64 + lane) * 8) = o;
  } else {
    int i = (b - nwb) * 256 + threadIdx.x;
    if (i < N) deg[i] = 0;
  }
}

// ---- stage1: k_in (blocks < nin) in parallel with degree histogram ----
__global__ __launch_bounds__(256) void k_stage1(const float* __restrict__ x,
    const unsigned short* __restrict__ wp,   // pair 0 (sc, dp)
    const float* __restrict__ scb, const float* __restrict__ dpb,
    unsigned short* __restrict__ sbuf, unsigned short* __restrict__ hbuf,
    const int* __restrict__ edst, int* __restrict__ deg, int N, int E, int nin){
  if ((int)blockIdx.x >= nin){
    int e = ((int)blockIdx.x - nin) * 256 + threadIdx.x;
    if (e < E) atomicAdd(&deg[edst[e]], 1);
    return;
  }
  __shared__ unsigned short tile[64 * WS];
  int tid = threadIdx.x, w = tid >> 6, lane = tid & 63, quad = lane >> 4, l16 = lane & 15;
  int nbb = blockIdx.x * 64;
  int nb = nbb + w * 16;
  int arow = min(nb + l16, N - 1);
  f32x4 acc[2][8];
  #pragma unroll
  for (int m = 0; m < 2; m++)
    #pragma unroll
    for (int t = 0; t < 8; t++) acc[m][t] = (f32x4){0.f, 0.f, 0.f, 0.f};
  #pragma unroll
  for (int kk = 0; kk < 4; kk++){
    const float* xp = x + (size_t)arow * D + kk * 32 + quad * 8;
    float4 xa = *(const float4*)xp;
    float4 xb = *(const float4*)(xp + 4);
    bf16x8 a;
    a[0] = (short)f2bf(xa.x); a[1] = (short)f2bf(xa.y);
    a[2] = (short)f2bf(xa.z); a[3] = (short)f2bf(xa.w);
    a[4] = (short)f2bf(xb.x); a[5] = (short)f2bf(xb.y);
    a[6] = (short)f2bf(xb.z); a[7] = (short)f2bf(xb.w);
    #pragma unroll
    for (int t = 0; t < 8; t++){
      size_t fo = (((size_t)(kk * 8 + t) * 2) * 64 + lane) * 8;
      bf16x8 b0 = *(const bf16x8*)(wp + fo);            // sc
      bf16x8 b1 = *(const bf16x8*)(wp + fo + 512);      // dp (half=1)
      acc[0][t] = __builtin_amdgcn_mfma_f32_16x16x32_bf16(a, b0, acc[0][t], 0, 0, 0);
      acc[1][t] = __builtin_amdgcn_mfma_f32_16x16x32_bf16(a, b1, acc[1][t], 0, 0, 0);
    }
  }
  #pragma unroll
  for (int m = 0; m < 2; m++){
    const float* bias = m ? dpb : scb;
    #pragma unroll
    for (int t = 0; t < 8; t++){
      float bv = bias[t * 16 + l16];
      #pragma unroll
      for (int r = 0; r < 4; r++){
        int nl = w * 16 + quad * 4 + r;
        float v = acc[m][t][r] + bv;
        if (m) v = gelu_fast(v);
        tile[nl * WS + t * 16 + l16] = f2bf(v);
      }
    }
    __syncthreads();
    unsigned short* dst = m ? hbuf : sbuf;
    #pragma unroll
    for (int i = 0; i < 4; i++){
      int c = tid + 256 * i;          // 1024 chunks of 8 shorts
      int nl = c >> 4, j = c & 15;
      int node = nbb + nl;
      if (node < N)
        *(bf16x8*)(dst + (size_t)node * D + j * 8) = *(const bf16x8*)(tile + nl * WS + j * 8);
    }
    __syncthreads();
  }
}

// ---- scan over 1024-chunks ----
__global__ __launch_bounds__(256) void k_scan1(const int* __restrict__ deg,
                                               int* __restrict__ off,
                                               int* __restrict__ partials, int n){
  __shared__ int sm[256];
  int t = threadIdx.x;
  int base = blockIdx.x * 1024 + t * 4;
  int d[4];
  #pragma unroll
  for (int i = 0; i < 4; i++) d[i] = (base + i < n) ? deg[base + i] : 0;
  int s = d[0] + d[1] + d[2] + d[3];
  sm[t] = s; __syncthreads();
  for (int ofs = 1; ofs < 256; ofs <<= 1){
    int v = (t >= ofs) ? sm[t - ofs] : 0;
    __syncthreads();
    sm[t] += v;
    __syncthreads();
  }
  int run = sm[t] - s;
  #pragma unroll
  for (int i = 0; i < 4; i++){ if (base + i < n) off[base + i] = run; run += d[i]; }
  if (t == 255) partials[blockIdx.x] = sm[255];
}

// ---- add partial prefix (inline scan of <=49 partials), init run, off[n] ----
__global__ void k_scan3(int* __restrict__ off, int* __restrict__ run,
                        const int* __restrict__ partials, int n, int E){
  int i = blockIdx.x * 256 + threadIdx.x;
  int pb = (blockIdx.x * 256) >> 10;    // uniform per block
  int add = 0;
  for (int j = 0; j < pb; j++) add += partials[j];
  if (i < n){
    int v = off[i] + add;
    off[i] = v; run[i] = v;
  }
  if (i == 0) off[n] = E;
}

__global__ void k_scatter(const int* __restrict__ srcn, const int* __restrict__ dstn,
                          int* __restrict__ run, int* __restrict__ csr, int E){
  int e = blockIdx.x * 256 + threadIdx.x;
  if (e < E){
    int pos = atomicAdd(&run[dstn[e]], 1);
    csr[pos] = srcn[e];
  }
}

// ---- mean aggregation: wave per node; quarter-wave (16 lanes x 16B) per
//      edge-stream; 4 streams/wave, unroll 4 -> 16 rows (4KB) in flight ----
__global__ __launch_bounds__(256) void k_agg(const unsigned short* __restrict__ h,
                                             const int* __restrict__ off,
                                             const int* __restrict__ csr,
                                             unsigned short* __restrict__ out, int N){
  int tid = threadIdx.x;
  int node = blockIdx.x * 4 + (tid >> 6);
  int lane = tid & 63;
  int q = lane >> 4, l16 = lane & 15;
  if (node >= N) return;
  int s0 = off[node], s1 = off[node + 1];
  int cnt = s1 - s0;
  float a[8];
  #pragma unroll
  for (int j = 0; j < 8; j++) a[j] = 0.f;
  int i = s0 + q;
  for (; i + 12 < s1; i += 16){
    int n0 = csr[i], n1 = csr[i + 4], n2 = csr[i + 8], n3 = csr[i + 12];
    uint4 v0 = *(const uint4*)(h + (size_t)n0 * D + l16 * 8);
    uint4 v1 = *(const uint4*)(h + (size_t)n1 * D + l16 * 8);
    uint4 v2 = *(const uint4*)(h + (size_t)n2 * D + l16 * 8);
    uint4 v3 = *(const uint4*)(h + (size_t)n3 * D + l16 * 8);
    a[0] += bf2f_lo(v0.x) + bf2f_lo(v1.x) + bf2f_lo(v2.x) + bf2f_lo(v3.x);
    a[1] += bf2f_hi(v0.x) + bf2f_hi(v1.x) + bf2f_hi(v2.x) + bf2f_hi(v3.x);
    a[2] += bf2f_lo(v0.y) + bf2f_lo(v1.y) + bf2f_lo(v2.y) + bf2f_lo(v3.y);
    a[3] += bf2f_hi(v0.y) + bf2f_hi(v1.y) + bf2f_hi(v2.y) + bf2f_hi(v3.y);
    a[4] += bf2f_lo(v0.z) + bf2f_lo(v1.z) + bf2f_lo(v2.z) + bf2f_lo(v3.z);
    a[5] += bf2f_hi(v0.z) + bf2f_hi(v1.z) + bf2f_hi(v2.z) + bf2f_hi(v3.z);
    a[6] += bf2f_lo(v0.w) + bf2f_lo(v1.w) + bf2f_lo(v2.w) + bf2f_lo(v3.w);
    a[7] += bf2f_hi(v0.w) + bf2f_hi(v1.w) + bf2f_hi(v2.w) + bf2f_hi(v3.w);
  }
  for (; i < s1; i += 4){
    int n0 = csr[i];
    uint4 v0 = *(const uint4*)(h + (size_t)n0 * D + l16 * 8);
    a[0] += bf2f_lo(v0.x); a[1] += bf2f_hi(v0.x);
    a[2] += bf2f_lo(v0.y); a[3] += bf2f_hi(v0.y);
    a[4] += bf2f_lo(v0.z); a[5] += bf2f_hi(v0.z);
    a[6] += bf2f_lo(v0.w); a[7] += bf2f_hi(v0.w);
  }
  // reduce across the 4 quarters
  #pragma unroll
  for (int j = 0; j < 8; j++){
    a[j] += __shfl_xor(a[j], 16);
    a[j] += __shfl_xor(a[j], 32);
  }
  float inv = 1.0f / (float)(cnt > 1 ? cnt : 1);
  if (q == 0){
    uint4 o;
    o.x = ((unsigned)f2bf(a[1] * inv) << 16) | (unsigned)f2bf(a[0] * inv);
    o.y = ((unsigned)f2bf(a[3] * inv) << 16) | (unsigned)f2bf(a[2] * inv);
    o.z = ((unsigned)f2bf(a[5] * inv) << 16) | (unsigned)f2bf(a[4] * inv);
    o.w = ((unsigned)f2bf(a[7] * inv) << 16) | (unsigned)f2bf(a[6] * inv);
    *(uint4*)(out + (size_t)node * D + l16 * 8) = o;
  }
}

// ---- SAGE layer: 16 nodes/wave, 64 nodes/block; acc = mean@wl.T + lb + h@wr.T;
//      LN; mode0: gelu -> bf16 hout (in-place safe); mode1: gelu(+shortcut) -> fp32 ----
__global__ __launch_bounds__(256) void k_g(
    const unsigned short* __restrict__ hin, const unsigned short* __restrict__ mbuf,
    const unsigned short* __restrict__ wp,   // pair (l, r)
    const float* __restrict__ lb, const float* __restrict__ gamma,
    const float* __restrict__ beta,
    const unsigned short* __restrict__ sbuf,
    unsigned short* __restrict__ hout, float* __restrict__ fout, int N, int mode){
  extern __shared__ char smraw[];
  unsigned short* stile = (unsigned short*)smraw;   // 64 x WS shorts
  float* ftile = (float*)smraw;                     // 64 x FS floats (mode1)
  int tid = threadIdx.x, w = tid >> 6, lane = tid & 63, quad = lane >> 4, l16 = lane & 15;
  int nbb = blockIdx.x * 64;
  int nb = nbb + w * 16;
  int arow = min(nb + l16, N - 1);
  f32x4 acc[8];
  #pragma unroll
  for (int t = 0; t < 8; t++) acc[t] = (f32x4){0.f, 0.f, 0.f, 0.f};
  #pragma unroll
  for (int kk = 0; kk < 4; kk++){
    int co = kk * 32 + quad * 8;
    bf16x8 am = *(const bf16x8*)(mbuf + (size_t)arow * D + co);
    bf16x8 ah = *(const bf16x8*)(hin + (size_t)arow * D + co);
    #pragma unroll
    for (int t = 0; t < 8; t++){
      size_t fo = (((size_t)(kk * 8 + t) * 2) * 64 + lane) * 8;
      bf16x8 bl = *(const bf16x8*)(wp + fo);
      bf16x8 br = *(const bf16x8*)(wp + fo + 512);
      acc[t] = __builtin_amdgcn_mfma_f32_16x16x32_bf16(am, bl, acc[t], 0, 0, 0);
      acc[t] = __builtin_amdgcn_mfma_f32_16x16x32_bf16(ah, br, acc[t], 0, 0, 0);
    }
  }
  float lbv[8], gv[8], bv[8];
  #pragma unroll
  for (int t = 0; t < 8; t++){
    lbv[t] = lb[t * 16 + l16];
    gv[t] = gamma[t * 16 + l16];
    bv[t] = beta[t * 16 + l16];
  }
  float mu[4], rs[4];
  #pragma unroll
  for (int r = 0; r < 4; r++){
    float s = 0.f, qq = 0.f;
    #pragma unroll
    for (int t = 0; t < 8; t++){
      float v = acc[t][r] + lbv[t];
      acc[t][r] = v;
      s += v; qq += v * v;
    }
    s += __shfl_xor(s, 1); qq += __shfl_xor(qq, 1);
    s += __shfl_xor(s, 2); qq += __shfl_xor(qq, 2);
    s += __shfl_xor(s, 4); qq += __shfl_xor(qq, 4);
    s += __shfl_xor(s, 8); qq += __shfl_xor(qq, 8);
    float m_ = s * (1.f / 128.f);
    mu[r] = m_;
    rs[r] = rsqrtf(qq * (1.f / 128.f) - m_ * m_ + 1e-5f);
  }
  if (mode == 0){
    #pragma unroll
    for (int t = 0; t < 8; t++)
      #pragma unroll
      for (int r = 0; r < 4; r++){
        int nl = w * 16 + quad * 4 + r;
        float v = (acc[t][r] - mu[r]) * rs[r] * gv[t] + bv[t];
        stile[nl * WS + t * 16 + l16] = f2bf(gelu_fast(v));
      }
    __syncthreads();
    #pragma unroll
    for (int i = 0; i < 4; i++){
      int c = tid + 256 * i;          // 1024 chunks of 8 shorts
      int nl = c >> 4, j = c & 15;
      int node = nbb + nl;
      if (node < N)
        *(bf16x8*)(hout + (size_t)node * D + j * 8) = *(const bf16x8*)(stile + nl * WS + j * 8);
    }
  } else {
    #pragma unroll
    for (int i = 0; i < 4; i++){
      int c = tid + 256 * i;
      int nl = c >> 4, j = c & 15;
      int node = nbb + nl;
      bf16x8 v = (bf16x8){0,0,0,0,0,0,0,0};
      if (node < N) v = *(const bf16x8*)(sbuf + (size_t)node * D + j * 8);
      *(bf16x8*)(stile + nl * WS + j * 8) = v;
    }
    __syncthreads();
    float sc[8][4];
    #pragma unroll
    for (int t = 0; t < 8; t++)
      #pragma unroll
      for (int r = 0; r < 4; r++){
        int nl = w * 16 + quad * 4 + r;
        sc[t][r] = bf2f(stile[nl * WS + t * 16 + l16]);
      }
    __syncthreads();
    #pragma unroll
    for (int t = 0; t < 8; t++)
      #pragma unroll
      for (int r = 0; r < 4; r++){
        int nl = w * 16 + quad * 4 + r;
        float v = (acc[t][r] - mu[r]) * rs[r] * gv[t] + bv[t];
        ftile[nl * FS + t * 16 + l16] = gelu_fast(v + sc[t][r]);
      }
    __syncthreads();
    #pragma unroll
    for (int i = 0; i < 8; i++){
      int c = tid + 256 * i;          // 2048 chunks of 4 floats
      int nl = c >> 5, j = c & 31;
      int node = nbb + nl;
      if (node < N)
        *(float4*)(fout + (size_t)node * D + j * 4) = *(const float4*)(ftile + nl * FS + j * 4);
    }
  }
}

extern "C" void kernel_launch(void* const* d_in, const int* in_sizes, int n_in,
                              void* d_out, int out_size, void* d_ws, size_t ws_size,
                              hipStream_t stream){
  const float* x     = (const float*)d_in[0];
  const int*   edges = (const int*)d_in[1];
  const float* dp_w  = (const float*)d_in[2];
  const float* dp_b  = (const float*)d_in[3];
  const float* sc_w  = (const float*)d_in[4];
  const float* sc_b  = (const float*)d_in[5];
  const float* g1_lw = (const float*)d_in[6];
  const float* g1_lb = (const float*)d_in[7];
  const float* g1_rw = (const float*)d_in[8];
  const float* n1_g  = (const float*)d_in[9];
  const float* n1_b  = (const float*)d_in[10];
  const float* g2_lw = (const float*)d_in[11];
  const float* g2_lb = (const float*)d_in[12];
  const float* g2_rw = (const float*)d_in[13];
  const float* n2_g  = (const float*)d_in[14];
  const float* n2_b  = (const float*)d_in[15];

  const int N = in_sizes[0] / D;
  const int E = in_sizes[1] / 2;
  const int* esrc = edges;
  const int* edst = edges + E;

  char* base = (char*)d_ws;
  size_t cur = 0;
  auto carve = [&](size_t b) -> char* {
    char* p = base + cur;
    cur = (cur + b + 255) & ~(size_t)255;
    return p;
  };
  int* off      = (int*)carve((size_t)(N + 1) * 4);
  int* run      = (int*)carve((size_t)N * 4);
  int* deg      = (int*)carve((size_t)N * 4);
  int* partials = (int*)carve(256 * 4);
  int* csr      = (int*)carve((size_t)E * 4);
  unsigned short* wb   = (unsigned short*)carve((size_t)3 * 32768 * 2);
  unsigned short* hbuf = (unsigned short*)carve((size_t)N * D * 2);
  unsigned short* mbuf = (unsigned short*)carve((size_t)N * D * 2);
  unsigned short* sbuf = (unsigned short*)carve((size_t)N * D * 2);

  unsigned short* wp0 = wb;                 // (sc, dp)
  unsigned short* wp1 = wb + 32768;         // (g1l, g1r)
  unsigned short* wp2 = wb + 2 * 32768;     // (g2l, g2r)

  float* out = (float*)d_out;

  const int nwb = 48;                       // 6 mats * 2048 threads / 256
  const int nzb = (N + 255) / 256;
  k_prep<<<nwb + nzb, 256, 0, stream>>>(sc_w, dp_w, g1_lw, g1_rw, g2_lw, g2_rw,
                                        wb, deg, N, nwb);

  const int nin = (N + 63) / 64;
  const int nhist = (E + 255) / 256;
  k_stage1<<<nin + nhist, 256, 0, stream>>>(x, wp0, sc_b, dp_b, sbuf, hbuf,
                                            edst, deg, N, E, nin);

  int nsb = (N + 1023) / 1024;
  k_scan1<<<nsb, 256, 0, stream>>>(deg, off, partials, N);
  k_scan3<<<(N + 255) / 256, 256, 0, stream>>>(off, run, partials, N, E);
  k_scatter<<<nhist, 256, 0, stream>>>(esrc, edst, run, csr, E);

  k_agg<<<(N + 3) / 4, 256, 0, stream>>>(hbuf, off, csr, mbuf, N);
  k_g<<<nin, 256, 17408, stream>>>(hbuf, mbuf, wp1, g1_lb, n1_g, n1_b,
                                   nullptr, hbuf, nullptr, N, 0);
  k_agg<<<(N + 3) / 4, 256, 0, stream>>>(hbuf, off, csr, mbuf, N);
  k_g<<<nin, 256, 33792, stream>>>(hbuf, mbuf, wp2, g2_lb, n2_g, n2_b,
                                   sbuf, nullptr, out, N, 1);
}